// Round 1
// baseline (327.968 us; speedup 1.0000x reference)
//
#include <hip/hip_runtime.h>

// MeanAggregator: out[b,:] = mean over DISTINCT nbrs[b,:] of features[idx,:]
// features: [N=200000, D=256] f32 (204.8 MB); nbrs: [B=32768, S=10]; out: [B, 256] f32
//
// Two-phase strategy:
//  Phase 1 (warm_llc): sequential grid-stride read of the whole feature
//    array. Features (204.8 MB) fit in the 256 MiB Infinity Cache, but the
//    harness's 819 MB poison fill flushes LLC every iteration. Streaming
//    the array back in costs ~33 us at copy BW and converts the random
//    gather from HBM-miss latency (~900 cy) to LLC-hit latency (~450-550
//    cy). The gather is MSHR/latency-bound (measured ~2 TB/s effective
//    vs 6.3 TB/s ceiling), so halving miss latency ~doubles its rate.
//  Phase 2 (gather): one wave per output row; lane i owns float4 at
//    columns [4i,4i+4) -> each feature-row read is one fully-coalesced
//    1 KB wave access. Neighbor indices go through the SCALAR path
//    (readfirstlane'd row id -> s_load), keeping the vector-memory queue
//    free for the 10 independent gathers.

#define AGG_S 10
#define AGG_D 256

__global__ __launch_bounds__(256) void MeanAggregator_warm_llc(
    const float4* __restrict__ feat4, long long n4)
{
    long long i = (long long)blockIdx.x * blockDim.x + threadIdx.x;
    const long long stride = (long long)gridDim.x * blockDim.x;
    float4 acc = make_float4(0.f, 0.f, 0.f, 0.f);
    for (; i < n4; i += stride) {
        float4 v = feat4[i];
        acc.x += v.x; acc.y += v.y; acc.z += v.z; acc.w += v.w;
    }
    // Keep the loads live without any store (rule #17: empty asm sink).
    asm volatile("" :: "v"(acc.x), "v"(acc.y), "v"(acc.z), "v"(acc.w));
}

__global__ __launch_bounds__(256) void MeanAggregator_58514634441194_kernel(
    const float* __restrict__ feat,
    const int* __restrict__ nbrs,
    float* __restrict__ out,
    int B)
{
    const int wave = (blockIdx.x * blockDim.x + threadIdx.x) >> 6;  // row id
    const int lane = threadIdx.x & 63;
    if (wave >= B) return;

    // Row id is wave-uniform; readfirstlane makes that provable so the
    // nbrs pointer lands in SGPRs and the 10 index loads take the scalar
    // (SMEM) path instead of 10 same-address vector loads.
    const int wrow = __builtin_amdgcn_readfirstlane(wave);
    const int* __restrict__ row = nbrs + (size_t)wrow * AGG_S;
    int idx[AGG_S];
#pragma unroll
    for (int s = 0; s < AGG_S; ++s) idx[s] = row[s];

    // First-occurrence weights: w[s] = 0 if idx[s] appeared at some j < s.
    // Pure VALU; overlaps with the gather loads below.
    float w[AGG_S];
    float cnt = 0.0f;
#pragma unroll
    for (int s = 0; s < AGG_S; ++s) {
        bool dup = false;
#pragma unroll
        for (int j = 0; j < AGG_S; ++j) {
            if (j < s) dup |= (idx[j] == idx[s]);
        }
        w[s] = dup ? 0.0f : 1.0f;
        cnt += w[s];
    }

    // Gather + weighted accumulate. All 10 loads independent -> 10 vector
    // loads in flight per wave before the first vmcnt wait.
    float4 acc = make_float4(0.f, 0.f, 0.f, 0.f);
#pragma unroll
    for (int s = 0; s < AGG_S; ++s) {
        const float4* __restrict__ fr =
            (const float4*)(feat + (size_t)idx[s] * AGG_D);
        float4 v = fr[lane];
        acc.x += w[s] * v.x;
        acc.y += w[s] * v.y;
        acc.z += w[s] * v.z;
        acc.w += w[s] * v.w;
    }

    const float inv = 1.0f / cnt;
    acc.x *= inv; acc.y *= inv; acc.z *= inv; acc.w *= inv;

    ((float4*)(out + (size_t)wave * AGG_D))[lane] = acc;
}

extern "C" void kernel_launch(void* const* d_in, const int* in_sizes, int n_in,
                              void* d_out, int out_size, void* d_ws, size_t ws_size,
                              hipStream_t stream)
{
    const float* feat = (const float*)d_in[0];
    const int*   nbrs = (const int*)d_in[1];
    float*       out  = (float*)d_out;

    const int B = in_sizes[1] / AGG_S;            // 32768
    const long long n4 = (long long)in_sizes[0] / 4;  // feature float4 count

    // Phase 1: warm the Infinity Cache with a streaming read of features.
    // 2048 blocks (8/CU) x 256 threads, grid-stride.
    MeanAggregator_warm_llc<<<2048, 256, 0, stream>>>(
        (const float4*)feat, n4);

    // Phase 2: gather (stream order = completion barrier after warm).
    const int threads = 256;                      // 4 waves/block
    const int rows_per_block = threads / 64;
    const int blocks = (B + rows_per_block - 1) / rows_per_block;
    MeanAggregator_58514634441194_kernel<<<blocks, threads, 0, stream>>>(
        feat, nbrs, out, B);
}

// Round 4
// 287.217 us; speedup vs baseline: 1.1419x; 1.1419x over previous
//
#include <hip/hip_runtime.h>

// MeanAggregator: out[b,:] = mean over DISTINCT nbrs[b,:] of features[idx,:]
// features: [N=200000, D=256] f32 (204.8 MB); nbrs: [B=32768, S=10]; out: [B,256] f32
//
// One wave per output row; lane i owns float4 at columns [4i,4i+4) so each
// feature-row read is one fully-coalesced 1 KB wave access (16 cache lines).
//
// This revision targets OCCUPANCY x MLP (outstanding-line concurrency):
//  - neighbor indices are wave-uniform -> readfirstlane forces them into
//    SGPRs (scalar loads, scalar address math). All 10 gathers then use the
//    saddr form (SGPR base + one shared lane*16 voffset VGPR).
//  - VGPR budget ~52 (40 in-flight data + 4 acc + temps) -> <=64 band ->
//    32 waves/CU instead of 16 (m69: residency halves at VGPR=64).
//    __launch_bounds__(256,8) pins 8 waves/SIMD.
//  - 10-deep load batch kept fully in flight before first use (separate
//    load loop / accumulate loop, both unrolled -> static indexing, no
//    scratch).
//  - nontemporal store for out (write-only; don't evict feature lines from
//    LLC -- they serve the ~1.64x cross-row reuse). Store goes through a
//    native ext_vector_type: __builtin_nontemporal_store rejects HIP's
//    struct-wrapped float4.
// Warm-LLC pass from round 1 reverted: measured null on the gather,
// pure +39 us cost.
// (Round 3 was an infra failure: input npz CRC error during push; kernel
// never ran. Identical resubmission.)

#define AGG_S 10
#define AGG_D 256

typedef __attribute__((ext_vector_type(4))) float f32x4;

__global__ __launch_bounds__(256, 8) void MeanAggregator_58514634441194_kernel(
    const float* __restrict__ feat,
    const int* __restrict__ nbrs,
    float* __restrict__ out,
    int B)
{
    const int tid  = blockIdx.x * blockDim.x + threadIdx.x;
    const int lane = threadIdx.x & 63;
    // tid>>6 is wave-uniform; readfirstlane makes that provable -> row id,
    // nbrs pointer, and all index loads take the scalar path.
    const int wave = __builtin_amdgcn_readfirstlane(tid >> 6);
    if (wave >= B) return;

    const int* __restrict__ row = nbrs + (size_t)wave * AGG_S;
    int idx[AGG_S];
#pragma unroll
    for (int s = 0; s < AGG_S; ++s)
        idx[s] = __builtin_amdgcn_readfirstlane(row[s]);

    // First-occurrence weights: w[s] = 0 if idx[s] appeared at some j < s.
    // All operands wave-uniform -> SALU/VALU-cheap, overlaps with loads.
    float w[AGG_S];
    float cnt = 0.0f;
#pragma unroll
    for (int s = 0; s < AGG_S; ++s) {
        bool dup = false;
#pragma unroll
        for (int j = 0; j < AGG_S; ++j) {
            if (j < s) dup |= (idx[j] == idx[s]);
        }
        w[s] = dup ? 0.0f : 1.0f;
        cnt += w[s];
    }

    // Issue all 10 gathers back-to-back (10 outstanding vmem instrs = 160
    // lines in flight per wave before the first vmcnt wait).
    float4 v[AGG_S];
#pragma unroll
    for (int s = 0; s < AGG_S; ++s) {
        const float4* __restrict__ p =
            (const float4*)(feat + (size_t)idx[s] * AGG_D);
        v[s] = p[lane];
    }

    // Consume in issue order: v[0] is ready first (in-order return), so the
    // FMA chain overlaps the tail loads.
    float4 acc = make_float4(0.f, 0.f, 0.f, 0.f);
#pragma unroll
    for (int s = 0; s < AGG_S; ++s) {
        acc.x = fmaf(w[s], v[s].x, acc.x);
        acc.y = fmaf(w[s], v[s].y, acc.y);
        acc.z = fmaf(w[s], v[s].z, acc.z);
        acc.w = fmaf(w[s], v[s].w, acc.w);
    }

    const float inv = 1.0f / cnt;
    acc.x *= inv; acc.y *= inv; acc.z *= inv; acc.w *= inv;

    f32x4 accv;
    accv.x = acc.x; accv.y = acc.y; accv.z = acc.z; accv.w = acc.w;
    f32x4* __restrict__ dst = (f32x4*)(out + (size_t)wave * AGG_D) + lane;
    __builtin_nontemporal_store(accv, dst);
}

extern "C" void kernel_launch(void* const* d_in, const int* in_sizes, int n_in,
                              void* d_out, int out_size, void* d_ws, size_t ws_size,
                              hipStream_t stream)
{
    const float* feat = (const float*)d_in[0];
    const int*   nbrs = (const int*)d_in[1];
    float*       out  = (float*)d_out;

    const int B = in_sizes[1] / AGG_S;           // 32768
    const int threads = 256;                     // 4 waves/block
    const int rows_per_block = threads / 64;
    const int blocks = (B + rows_per_block - 1) / rows_per_block;

    MeanAggregator_58514634441194_kernel<<<blocks, threads, 0, stream>>>(
        feat, nbrs, out, B);
}